// Round 11
// baseline (393.195 us; speedup 1.0000x reference)
//
#include <hip/hip_runtime.h>
#include <hip/hip_bf16.h>
#include <stdint.h>

typedef unsigned short u16;
typedef __attribute__((ext_vector_type(8))) short bf16x8;
typedef __attribute__((ext_vector_type(4))) float f32x4;

#define DI __device__ __forceinline__

DI float b2f(u16 u) { return __uint_as_float(((uint32_t)u) << 16); }
DI u16 f2b(float f) {
  uint32_t u = __float_as_uint(f);
  u += 0x7fff + ((u >> 16) & 1);   // RNE
  return (u16)(u >> 16);
}

DI void gld_lds16(const u16* g, u16* l) {
  __builtin_amdgcn_global_load_lds((const __attribute__((address_space(1))) void*)g,
                                   (__attribute__((address_space(3))) void*)l,
                                   16, 0, 0);
}

// ---------------------------------------------------------------------------
// PREP (one launch):
//  [0,640)      GroupNorm_s(x) -> W0 [n][p][c] (XCD-clustered work ids)
//  [640,1664)   convert 8 weight matrices f32->bf16; transposes written for
//               wq->11, wk->16, wv->8, wqt->15, wkt->20, wvt->12 (slot units)
//  [1664,1672)  pack 8 biases (f32)
//  [1672,1674)  bvv  = Wo.bv         at bdst+4096
//  [1674,1676)  bovt = Wot.bvt + bot at bdst+4608
//  [1676,1678)  w_s  = Wk^T.bq       at bdst+5120  (scores col-bias vector)
//  [1678,1680)  w_t  = Wkt^T.bqt     at bdst+5632  (temporal col-bias vector)
//  [1680,1760)  zero softmax stats (20x1024 f32) at bdst+8192
// ---------------------------------------------------------------------------
__global__ __launch_bounds__(256)
void prep(const float* __restrict__ x, const float* __restrict__ gamma,
          const float* __restrict__ beta, u16* __restrict__ gnout,
          const float* __restrict__ w0, const float* __restrict__ w1,
          const float* __restrict__ w2, const float* __restrict__ w3,
          const float* __restrict__ w4, const float* __restrict__ w5,
          const float* __restrict__ w6, const float* __restrict__ w7,
          const float* __restrict__ b0, const float* __restrict__ b1,
          const float* __restrict__ b2, const float* __restrict__ b3,
          const float* __restrict__ b4, const float* __restrict__ b5,
          const float* __restrict__ b6, const float* __restrict__ b7,
          u16* __restrict__ dst, float* __restrict__ bdst)
{
  const int t = threadIdx.x;
  if (blockIdx.x < 640) {                   // ---- GroupNorm_s ----
    const int w = (blockIdx.x & 7) * 80 + (blockIdx.x >> 3);  // XCD-cluster
    const int n = w >> 5, g = w & 31;
    const int C = 512, HW = 1024;
    const float* xg = x + ((long)n * C + g * 16) * HW;
    float s = 0.f, ss = 0.f;
    for (int ch = t; ch < 4096; ch += 256) {
      float4 u = *(const float4*)(xg + ch * 4);
      s += u.x + u.y + u.z + u.w;
      ss += u.x * u.x + u.y * u.y + u.z * u.z + u.w * u.w;
    }
#pragma unroll
    for (int off = 32; off > 0; off >>= 1) { s += __shfl_xor(s, off); ss += __shfl_xor(ss, off); }
    __shared__ float rs[4], rss[4];
    if ((t & 63) == 0) { rs[t >> 6] = s; rss[t >> 6] = ss; }
    __syncthreads();
    s  = rs[0] + rs[1] + rs[2] + rs[3];
    ss = rss[0] + rss[1] + rss[2] + rss[3];
    const float mu = s * (1.f / 16384.f);
    const float var = ss * (1.f / 16384.f) - mu * mu;
    const float rstd = rsqrtf(var + 1e-6f);
    float gm[16], bt[16];
#pragma unroll
    for (int i = 0; i < 16; ++i) {
      float ga = gamma[g * 16 + i];
      gm[i] = ga * rstd;
      bt[i] = beta[g * 16 + i] - mu * ga * rstd;
    }
    for (int p = t; p < 1024; p += 256) {
      alignas(16) u16 vals[16];
#pragma unroll
      for (int i = 0; i < 16; ++i)
        vals[i] = f2b(xg[(long)i * HW + p] * gm[i] + bt[i]);
      u16* dp = gnout + ((long)n * HW + p) * C + g * 16;
      *(uint4*)dp       = *(const uint4*)&vals[0];
      *(uint4*)(dp + 8) = *(const uint4*)&vals[8];
    }
    return;
  }
  const int sb = blockIdx.x - 640;          // ---- setup ----
  if (sb >= 1040) {                         // zero softmax stats
    bdst[8192 + (sb - 1040) * 256 + t] = 0.f;
    return;
  }
  if (sb >= 1038) {                         // w_t = Wkt^T . bqt
    const int d = (sb - 1038) * 256 + t;
    float acc = 0.f;
    for (int e = 0; e < 512; ++e) acc += w5[(long)e * 512 + d] * b4[e];
    bdst[5632 + d] = acc;
    return;
  }
  if (sb >= 1036) {                         // w_s = Wk^T . bq
    const int d = (sb - 1036) * 256 + t;
    float acc = 0.f;
    for (int e = 0; e < 512; ++e) acc += w1[(long)e * 512 + d] * b0[e];
    bdst[5120 + d] = acc;
    return;
  }
  if (sb >= 1034) {                         // bovt = Wot.bvt + bot
    const int a = (sb - 1034) * 256 + t;
    float acc = 0.f;
    for (int c = 0; c < 512; ++c) acc += w7[a * 512 + c] * b6[c];
    bdst[4608 + a] = acc + b7[a];
    return;
  }
  if (sb >= 1032) {                         // bvv = Wo . bv
    const int a = (sb - 1032) * 256 + t;
    float acc = 0.f;
    for (int c = 0; c < 512; ++c) acc += w3[a * 512 + c] * b2[c];
    bdst[4096 + a] = acc;
    return;
  }
  if (sb >= 1024) {                         // biases
    const float* bs8[8] = {b0, b1, b2, b3, b4, b5, b6, b7};
    const int a = sb - 1024;
    bdst[a * 512 + t] = bs8[a][t];
    bdst[a * 512 + t + 256] = bs8[a][t + 256];
    return;
  }
  const float* srcs[8] = {w0, w1, w2, w3, w4, w5, w6, w7};
  const int mat = sb >> 7;
  const int i = (((sb & 127) << 8) + t) * 8;
  const float* s = srcs[mat];
  float4 a = *(const float4*)(s + i);
  float4 b = *(const float4*)(s + i + 4);
  alignas(16) u16 v[8] = {f2b(a.x), f2b(a.y), f2b(a.z), f2b(a.w),
                          f2b(b.x), f2b(b.y), f2b(b.z), f2b(b.w)};
  *(uint4*)(dst + (long)mat * 262144 + i) = *(const uint4*)v;
  // transposes feeding the z=4 weight GEMM (slot layout, stride-4 families):
  //   A:  3=wo, 7=wot, 11=WqT, 15=WqtT;  Bt: 8=WvT, 12=WvtT, 16=WkT, 20=WktT
  const int tmap[8] = {11, 16, 8, -1, 15, 20, 12, -1};
  const int ts = tmap[mat];
  if (ts >= 0) {
    const int row = i >> 9, col = i & 511;
#pragma unroll
    for (int j = 0; j < 8; ++j) dst[(long)ts * 262144 + (col + j) * 512 + row] = v[j];
  }
}

// ---------------------------------------------------------------------------
// Shared GEMM body: BM=BN=128, BK=32, 256 threads (4 waves 2x2 of 64x64),
// 16x16x32 bf16 MFMA, XOR-swizzled LDS (0 conflicts), LDS double-buffer.
// BIASMODE: 0 none, 1 bias[row], 2 bias[col].
// SMEXP: epilogue writes exp((acc+colbias)*alpha), row sums -> stats.
// COLSCALE: epilogue multiplies col cc by 1/stats[stb+cc].
// COLB: per-z column bias (cbias[cbb+cc]) added PRE-exp (QK bias fold term).
// ---------------------------------------------------------------------------
template<int OUTF32, int BIASMODE, int RESID, int SMEXP, int COLSCALE, int COLB>
DI void gemm_body(const u16* __restrict__ Ab, long lda,
                  const u16* __restrict__ Bb, long ldb,
                  void* __restrict__ C, long cb,
                  const float* __restrict__ bias,
                  const float* __restrict__ resid, long rb,
                  int N, int K, float alpha,
                  float* __restrict__ stats, long stb,
                  const float* __restrict__ cbias, long cbb,
                  int m0, int n0, u16* lA, u16* lB)
{
  const int t = threadIdx.x;
  const int lane = t & 63;
  const int wid = t >> 6;
  const int row = t >> 2;                              // 0..63
  const int kc  = (((t & 3) ^ ((t >> 3) & 3)) << 3);   // swizzled staged chunk

  f32x4 acc[4][4];
#pragma unroll
  for (int i = 0; i < 4; ++i)
#pragma unroll
    for (int j = 0; j < 4; ++j) acc[i][j] = (f32x4){0.f, 0.f, 0.f, 0.f};

  const int ml = lane & 15, qd = lane >> 4;
  const int koff = ((qd ^ ((ml >> 1) & 3)) << 3);      // swizzled read offset
  const int wm = (wid >> 1) * 64, wn = (wid & 1) * 64;

  auto stage = [&](int bsel, int k0) {
    const u16* Ap = Ab + (long)(m0 + row) * lda + (k0 + kc);
    const u16* Bp = Bb + (long)(n0 + row) * ldb + (k0 + kc);
    u16* la = lA + bsel * 4096 + wid * 512;
    u16* lb = lB + bsel * 4096 + wid * 512;
    gld_lds16(Ap, la);
    gld_lds16(Ap + 64 * lda, la + 2048);
    gld_lds16(Bp, lb);
    gld_lds16(Bp + 64 * ldb, lb + 2048);
  };

  const int niter = K >> 5;
  stage(0, 0);
  for (int i = 0; i < niter; ++i) {
    __syncthreads();                       // drains buf[i&1] prefetch
    if (i + 1 < niter) stage((i + 1) & 1, (i + 1) << 5);  // overlaps MFMA below
    const u16* la = lA + (i & 1) * 4096;
    const u16* lb = lB + (i & 1) * 4096;
    bf16x8 af[4], bfr[4];
#pragma unroll
    for (int x = 0; x < 4; ++x)
      af[x] = *(const bf16x8*)&la[(wm + x * 16 + ml) * 32 + koff];
#pragma unroll
    for (int y = 0; y < 4; ++y)
      bfr[y] = *(const bf16x8*)&lb[(wn + y * 16 + ml) * 32 + koff];
#pragma unroll
    for (int x = 0; x < 4; ++x)
#pragma unroll
      for (int y = 0; y < 4; ++y)
        acc[x][y] = __builtin_amdgcn_mfma_f32_16x16x32_bf16(af[x], bfr[y], acc[x][y], 0, 0, 0);
  }

  float inv[4], bcol[4], cbl[4];
  if (COLSCALE) {
#pragma unroll
    for (int j = 0; j < 4; ++j)
      inv[j] = 1.f / stats[stb + n0 + wn + j * 16 + ml];
  }
  if (BIASMODE == 2) {
#pragma unroll
    for (int j = 0; j < 4; ++j) bcol[j] = bias[n0 + wn + j * 16 + ml];
  }
  if (COLB) {
#pragma unroll
    for (int j = 0; j < 4; ++j) cbl[j] = cbias[cbb + n0 + wn + j * 16 + ml];
  }
  if (SMEXP) {
    float rs[16];
#pragma unroll
    for (int s = 0; s < 16; ++s) rs[s] = 0.f;
#pragma unroll
    for (int i = 0; i < 4; ++i)
#pragma unroll
      for (int j = 0; j < 4; ++j)
#pragma unroll
        for (int r2 = 0; r2 < 4; ++r2) {
          float sv = acc[i][j][r2];
          if (COLB) sv += cbl[j];
          float e = __expf(sv * alpha);
          acc[i][j][r2] = e;
          rs[i * 4 + r2] += e;
        }
#pragma unroll
    for (int m = 1; m < 16; m <<= 1)
#pragma unroll
      for (int s = 0; s < 16; ++s) rs[s] += __shfl_xor(rs[s], m);
    if (ml == 0) {
#pragma unroll
      for (int i = 0; i < 4; ++i)
#pragma unroll
        for (int r2 = 0; r2 < 4; ++r2)
          atomicAdd(&stats[stb + m0 + wm + i * 16 + qd * 4 + r2], rs[i * 4 + r2]);
    }
  }

#pragma unroll
  for (int i = 0; i < 4; ++i) {
#pragma unroll
    for (int r2 = 0; r2 < 4; ++r2) {
      const int rr = m0 + wm + i * 16 + qd * 4 + r2;  // C/D row = quad*4+reg
      const float brow = (BIASMODE == 1) ? bias[rr] : 0.f;
      const long base = (long)rr * N + n0 + wn + ml;  // col = lane&15 (+j*16)
#pragma unroll
      for (int j = 0; j < 4; ++j) {
        float v = acc[i][j][r2];
        if (!SMEXP) v *= alpha;
        if (COLSCALE) v *= inv[j];
        if (BIASMODE == 1) v += brow;
        if (BIASMODE == 2) v += bcol[j];
        const long ix = base + j * 16;
        if (RESID) v += resid[rb + ix];
        if (OUTF32) ((float*)C)[cb + ix] = v;
        else        ((u16*)C)[cb + ix] = f2b(v);
      }
    }
  }
}

// Generic batched GEMM with z-clustered XCD remap (verified R7).
template<int OUTF32, int BIASMODE, int RESID, int SMEXP, int COLSCALE, int COLB>
__global__ __launch_bounds__(256)
void gemm_bt(const u16* __restrict__ A, long sA, long lda,
             const u16* __restrict__ B, long sB, long ldb,
             void* __restrict__ C, long sC,
             const float* __restrict__ bias,
             const float* __restrict__ resid, long sR,
             int N, int K, float alpha, float* __restrict__ stats,
             const float* __restrict__ cbias)
{
  __shared__ u16 lA[2 * 128 * 32];
  __shared__ u16 lB[2 * 128 * 32];
  const uint32_t nx = gridDim.x, ny = gridDim.y;
  const uint32_t tpz = nx * ny;
  const uint32_t nblk = tpz * gridDim.z;
  const uint32_t g = ((uint32_t)blockIdx.z * ny + blockIdx.y) * nx + blockIdx.x;
  const uint32_t idx = (g & 7u) * (nblk >> 3) + (g >> 3);
  const uint32_t bz = idx / tpz;
  const uint32_t r   = idx - bz * tpz;
  const int m0 = (int)(r / nx) * 128, n0 = (int)(r % nx) * 128;
  gemm_body<OUTF32, BIASMODE, RESID, SMEXP, COLSCALE, COLB>(
      A + bz * sA, lda, B + bz * sB, ldb, C, bz * sC, bias, resid, bz * sR,
      N, K, alpha, stats, (long)bz * 1024, cbias, (long)bz * 1024,
      m0, n0, lA, lB);
}

// ---------------------------------------------------------------------------
// Merged mk || vv || colterm launch (all depend only on prep + weight GEMM):
//  [0,640):    mkT = hn.M_s^T  (M=20480, N=512, K=512) -> W1 [20480][512]
//  [640,1280): vv  = Wov.hn^T + bvv (z=20, M=512, N=1024) -> W3 [20][c][p]
//  [1280,1360): colterm[row] = dot(hn[row], w_s) -> colt[20480] (f32)
// Partition offsets multiples of 8 keep XCD parity for the remaps.
// ---------------------------------------------------------------------------
__global__ __launch_bounds__(256)
void gemm_mkvv(const u16* __restrict__ hn, const u16* __restrict__ Ms,
               u16* __restrict__ mkout,
               const u16* __restrict__ Wov, u16* __restrict__ vvout,
               const float* __restrict__ bvv,
               const float* __restrict__ ws, float* __restrict__ colt)
{
  __shared__ u16 lA[2 * 128 * 32];
  __shared__ u16 lB[2 * 128 * 32];
  const long S = 524288;
  const int t = threadIdx.x;
  const uint32_t g = blockIdx.x;
  if (g < 640) {                            // ---- mkT ----
    const uint32_t idx = (g & 7u) * 80 + (g >> 3);
    const int m0 = (int)(idx >> 2) * 128, n0 = (int)(idx & 3u) * 128;
    gemm_body<0, 0, 0, 0, 0, 0>(hn, 512, Ms, 512, mkout, 0, nullptr,
                                nullptr, 0, 512, 512, 1.f, nullptr, 0,
                                nullptr, 0, m0, n0, lA, lB);
  } else if (g < 1280) {                    // ---- vv ----
    const uint32_t gg = g - 640;            // 640%8==0 keeps parity
    const uint32_t idx = (gg & 7u) * 80 + (gg >> 3);
    const uint32_t bz = idx >> 5;           // 32 tiles per z
    const uint32_t r = idx & 31u;
    const int m0 = (int)(r >> 3) * 128, n0 = (int)(r & 7u) * 128;
    gemm_body<0, 1, 0, 0, 0, 0>(Wov, 512, hn + (long)bz * S, 512, vvout,
                                (long)bz * S, bvv, nullptr, 0,
                                1024, 512, 1.f, nullptr, 0, nullptr, 0,
                                m0, n0, lA, lB);
  } else {                                  // ---- colterm (QK bias fold) ----
    const uint32_t gg = g - 1280;
    const int lane = t & 63, wv = t >> 6;
    float wsv[8];
#pragma unroll
    for (int u = 0; u < 8; ++u) wsv[u] = ws[lane * 8 + u];
    for (int rr = 0; rr < 64; ++rr) {
      const int row = gg * 256 + wv * 64 + rr;
      bf16x8 hv = *(const bf16x8*)(hn + (long)row * 512 + lane * 8);
      float a = 0.f;
#pragma unroll
      for (int u = 0; u < 8; ++u) a += b2f((u16)hv[u]) * wsv[u];
#pragma unroll
      for (int off = 32; off > 0; off >>= 1) a += __shfl_xor(a, off);
      if (lane == 0) colt[row] = a;
    }
  }
}

// ---------------------------------------------------------------------------
// GroupNorm with fused residual: spatio = x (f32) + h (bf16 conv out), then
// GroupNorm -> bf16 out TRANSPOSED to [n][p][c]. XCD-clustered work ids.
// ---------------------------------------------------------------------------
__global__ __launch_bounds__(256)
void groupnorm_resid(const u16* __restrict__ h, const float* __restrict__ x,
                     const float* __restrict__ gamma,
                     const float* __restrict__ beta, u16* __restrict__ out)
{
  const int C = 512, HW = 1024;
  const int w = (blockIdx.x & 7) * 80 + (blockIdx.x >> 3);    // XCD-cluster
  const int n = w >> 5, g = w & 31;
  const long base = ((long)n * C + g * 16) * HW;
  const float* xg = x + base;
  const u16*  hg = h + base;
  const int t = threadIdx.x;
  float s = 0.f, ss = 0.f;
  for (int ch = t; ch < 4096; ch += 256) {
    float4 u = *(const float4*)(xg + ch * 4);
    uint2 hv = *(const uint2*)(hg + ch * 4);
    float h0 = __uint_as_float(hv.x << 16);
    float h1 = __uint_as_float(hv.x & 0xffff0000u);
    float h2 = __uint_as_float(hv.y << 16);
    float h3 = __uint_as_float(hv.y & 0xffff0000u);
    float v0 = u.x + h0, v1 = u.y + h1, v2 = u.z + h2, v3 = u.w + h3;
    s += v0 + v1 + v2 + v3;
    ss += v0 * v0 + v1 * v1 + v2 * v2 + v3 * v3;
  }
#pragma unroll
  for (int off = 32; off > 0; off >>= 1) { s += __shfl_xor(s, off); ss += __shfl_xor(ss, off); }
  __shared__ float rs[4], rss[4];
  if ((t & 63) == 0) { rs[t >> 6] = s; rss[t >> 6] = ss; }
  __syncthreads();
  s  = rs[0] + rs[1] + rs[2] + rs[3];
  ss = rss[0] + rss[1] + rss[2] + rss[3];
  const float mu = s * (1.f / 16384.f);
  const float var = ss * (1.f / 16384.f) - mu * mu;
  const float rstd = rsqrtf(var + 1e-6f);
  float gm[16], bt[16];
#pragma unroll
  for (int i = 0; i < 16; ++i) {
    float ga = gamma[g * 16 + i];
    gm[i] = ga * rstd;
    bt[i] = beta[g * 16 + i] - mu * ga * rstd;
  }
  for (int p = t; p < 1024; p += 256) {
    alignas(16) u16 vals[16];
#pragma unroll
    for (int i = 0; i < 16; ++i)
      vals[i] = f2b((xg[(long)i * HW + p] + b2f(hg[(long)i * HW + p])) * gm[i] + bt[i]);
    u16* dst = out + ((long)n * HW + p) * C + g * 16;
    *(uint4*)dst       = *(const uint4*)&vals[0];
    *(uint4*)(dst + 8) = *(const uint4*)&vals[8];
  }
}

// ---------------------------------------------------------------------------
// Temporal attention (QK + Wovt folded): one WAVE per pixel (b,p).
// Q = hn_t row (also reused as V); K = mkt row (= hn_t.M_t^T). Bias fold:
// ct[j] = dot(hn_t[j], w_t) added to scores pre-softmax (row term cancels).
// Output htp' = sum_s att[i][s]*hn_t[s] -> [20480][512].
// ---------------------------------------------------------------------------
__global__ __launch_bounds__(256)
void temporal_attn(const u16* __restrict__ mkt, const u16* __restrict__ hn,
                   u16* __restrict__ htp, const float* __restrict__ wt)
{
  const int t = threadIdx.x;
  const int wv = t >> 6, lane = t & 63;
  const int pix = blockIdx.x * 4 + wv;      // 0..4095 = (b, p)
  const int b = pix >> 10, p = pix & 1023;
  const long fsh = 1024l * 512;             // frame stride (hn/mkt/htp)
  const long rowh = ((long)b * 5 * 1024 + p) * 512 + lane * 8;

  float wtv[8];
#pragma unroll
  for (int u = 0; u < 8; ++u) wtv[u] = wt[lane * 8 + u];

  float qf[5][8], kf[5][8];
#pragma unroll
  for (int f = 0; f < 5; ++f) {
    bf16x8 qv = *(const bf16x8*)(hn  + rowh + f * fsh);
    bf16x8 kv = *(const bf16x8*)(mkt + rowh + f * fsh);
#pragma unroll
    for (int u = 0; u < 8; ++u) { qf[f][u] = b2f((u16)qv[u]); kf[f][u] = b2f((u16)kv[u]); }
  }
  float sc[30];                             // 25 scores + 5 colterms
#pragma unroll
  for (int i = 0; i < 5; ++i)
#pragma unroll
    for (int j = 0; j < 5; ++j) {
      float a = 0.f;
#pragma unroll
      for (int u = 0; u < 8; ++u) a += qf[i][u] * kf[j][u];
      sc[i * 5 + j] = a;
    }
#pragma unroll
  for (int f = 0; f < 5; ++f) {
    float a = 0.f;
#pragma unroll
    for (int u = 0; u < 8; ++u) a += qf[f][u] * wtv[u];
    sc[25 + f] = a;
  }
#pragma unroll
  for (int m = 1; m < 64; m <<= 1)
#pragma unroll
    for (int s = 0; s < 30; ++s) sc[s] += __shfl_xor(sc[s], m);

  const float scale = 0.04419417382415922f;  // 512^-0.5
  float att[5][5];
#pragma unroll
  for (int i = 0; i < 5; ++i) {
    float sf[5];
#pragma unroll
    for (int j = 0; j < 5; ++j) sf[j] = sc[i * 5 + j] + sc[25 + j];
    float m = sf[0];
#pragma unroll
    for (int j = 1; j < 5; ++j) m = fmaxf(m, sf[j]);
    float ssum = 0.f;
#pragma unroll
    for (int j = 0; j < 5; ++j) { att[i][j] = __expf((sf[j] - m) * scale); ssum += att[i][j]; }
    float inv = 1.f / ssum;
#pragma unroll
    for (int j = 0; j < 5; ++j) att[i][j] *= inv;
  }

  float of[5][8];
#pragma unroll
  for (int i = 0; i < 5; ++i)
#pragma unroll
    for (int u = 0; u < 8; ++u) of[i][u] = 0.f;
#pragma unroll
  for (int s = 0; s < 5; ++s)               // V = hn_t rows, already in qf
#pragma unroll
    for (int u = 0; u < 8; ++u) {
      const float vf = qf[s][u];
#pragma unroll
      for (int i = 0; i < 5; ++i) of[i][u] += att[i][s] * vf;
    }
#pragma unroll
  for (int i = 0; i < 5; ++i) {
    alignas(16) u16 ob[8];
#pragma unroll
    for (int u = 0; u < 8; ++u) ob[u] = f2b(of[i][u]);
    *(uint4*)(htp + rowh + i * fsh) = *(const uint4*)ob;
  }
}

// ---------------------------------------------------------------------------
extern "C" void kernel_launch(void* const* d_in, const int* in_sizes, int n_in,
                              void* d_out, int out_size, void* d_ws, size_t ws_size,
                              hipStream_t stream)
{
  const float* x   = (const float*)d_in[0];
  const float* wq  = (const float*)d_in[1];
  const float* bq  = (const float*)d_in[2];
  const float* wk  = (const float*)d_in[3];
  const float* bk  = (const float*)d_in[4];
  const float* wv  = (const float*)d_in[5];
  const float* bv  = (const float*)d_in[6];
  const float* wo  = (const float*)d_in[7];
  const float* bo  = (const float*)d_in[8];
  const float* wqt = (const float*)d_in[9];
  const float* bqt = (const float*)d_in[10];
  const float* wkt = (const float*)d_in[11];
  const float* bkt = (const float*)d_in[12];
  const float* wvt = (const float*)d_in[13];
  const float* bvt = (const float*)d_in[14];
  const float* wot = (const float*)d_in[15];
  const float* bot = (const float*)d_in[16];
  const float* gs  = (const float*)d_in[17];
  const float* bs  = (const float*)d_in[18];
  const float* gt  = (const float*)d_in[19];
  const float* btt = (const float*)d_in[20];

  // ws = 256 MiB. Slots W0..W7 (8 x 20 MB), weights Wt (22 x 0.5 MB), biases.
  const long U = 20l * 1024 * 512;          // elements per slot
  u16* W0 = (u16*)d_ws;
  u16* W1 = W0 + U;                          // mkT / mkt [20480][512]
  u16* W3 = W0 + 3 * U;                      // vv [20][c][p]
  u16* W4 = W0 + 4 * U;                      // W4..W5 scores [20][1024][1024]
  u16* W6 = W0 + 6 * U;                      // hsp_conv [20][c][p]
  u16* W7 = W0 + 7 * U;                      // hn_t [n][p][c]
  u16* Wt = W0 + 8 * U;
  // weight slot layout (stride-4 families for the z=4 weight GEMM):
  //  0..7 converted; A: 3=wo,7=wot,11=WqT,15=WqtT; Bt: 8=WvT,12=WvtT,16=WkT,
  //  20=WktT; C: 9=Wov,13=Wovt,17=M_s,21=M_t.
  u16* wo_b   = Wt + 3 * 262144;
  u16* wvT_b  = Wt + 8 * 262144;
  u16* Wovs   = Wt + 9 * 262144;
  u16* Wovt_b = Wt + 13 * 262144;
  u16* Ms_b   = Wt + 17 * 262144;
  u16* Mt_b   = Wt + 21 * 262144;
  float* Bf = (float*)(Wt + 22 * 262144);    // biases; bvv@4096; bovt@4608;
  float* Ws_v = Bf + 5120;                   // w_s vector
  float* Wt_v = Bf + 5632;                   // w_t vector
  float* Stats = Bf + 8192;                  // 20x1024 softmax row sums
  float* Colt  = Bf + 28672;                 // 20x1024 scores col-bias

  const long S  = 524288;                   // 1024*512 per-image stride
  const long S2 = 1048576;                  // 1024*1024 per-image stride
  const float scale = 0.04419417382415922f; // 512^-0.5
  dim3 blk(256);

  // prep: GroupNorm_s + weight convert (+6 transposes) + biases + folded
  // bias vectors + stats zero
  prep<<<1760, blk, 0, stream>>>(x, gs, bs, W0,
                                 wq, wk, wv, wo, wqt, wkt, wvt, wot,
                                 bq, bk, bv, bo, bqt, bkt, bvt, bot, Wt, Bf);

  // Weight GEMM (z=4): Wov = Wo.Wv; Wovt = Wot.Wvt; M_s = Wq^T.Wk;
  // M_t = Wqt^T.Wkt  (uniform stride-4-slot families)
  gemm_bt<0, 0, 0, 0, 0, 0><<<dim3(4, 4, 4), blk, 0, stream>>>(
      wo_b, 4 * 262144, 512, wvT_b, 4 * 262144, 512, Wovs, 4 * 262144,
      nullptr, nullptr, 0, 512, 512, 1.f, nullptr, nullptr);

  // mkT || vv || colterm merged: 640 + 640 + 80 blocks
  gemm_mkvv<<<1360, blk, 0, stream>>>(W0, Ms_b, W1, Wovs, W3, Bf + 4096,
                                      Ws_v, Colt);

  // att_exp = exp((hn.mkT^T + colterm) * scale) -> W4W5; row sums -> Stats
  gemm_bt<0, 0, 0, 1, 0, 1><<<dim3(8, 8, 20), blk, 0, stream>>>(
      W0, S, 512, W1, S, 512, W4, S2, nullptr, nullptr, 0,
      1024, 512, scale, Stats, Colt);
  // hsp_conv = (vv.att_exp^T) * inv[pq] + bo: z=20, M=c', N=pq, K=pk -> W6
  gemm_bt<0, 1, 0, 0, 1, 0><<<dim3(8, 4, 20), blk, 0, stream>>>(
      W3, S, 1024, W4, S2, 1024, W6, S, Bf + 1536, nullptr, 0,
      1024, 1024, 1.f, Stats, nullptr);
  // hn_t = GroupNorm_t(x + W6) -> W7 [n][p][c]  (resid fused here)
  groupnorm_resid<<<640, blk, 0, stream>>>(W6, x, gt, btt, W7);
  // mkt = hn_t.M_t^T: M=20480, N=512, K=512 -> W1 [20480][512]
  gemm_bt<0, 0, 0, 0, 0, 0><<<dim3(4, 160, 1), blk, 0, stream>>>(
      W7, 0, 512, Mt_b, 0, 512, W1, 0, nullptr, nullptr, 0,
      512, 512, 1.f, nullptr, nullptr);
  // per-pixel 5x5 temporal attention (Q=V=hn_t, K=mkt) -> W0 htp' [20480][512]
  temporal_attn<<<1024, blk, 0, stream>>>(W1, W7, W0, Wt_v);
  // out = x + Wovt.htp' + (Wot.bvt + bot) -> d_out f32, z=20
  gemm_bt<1, 1, 1, 0, 0, 0><<<dim3(8, 4, 20), blk, 0, stream>>>(
      Wovt_b, 0, 512, W0, S, 512, (float*)d_out, S, Bf + 4608, x, S,
      1024, 512, 1.f, nullptr, nullptr);
}

// Round 12
// 376.829 us; speedup vs baseline: 1.0434x; 1.0434x over previous
//
#include <hip/hip_runtime.h>
#include <hip/hip_bf16.h>
#include <stdint.h>

typedef unsigned short u16;
typedef __attribute__((ext_vector_type(8))) short bf16x8;
typedef __attribute__((ext_vector_type(4))) float f32x4;

#define DI __device__ __forceinline__

DI float b2f(u16 u) { return __uint_as_float(((uint32_t)u) << 16); }
DI u16 f2b(float f) {
  uint32_t u = __float_as_uint(f);
  u += 0x7fff + ((u >> 16) & 1);   // RNE
  return (u16)(u >> 16);
}

DI void gld_lds16(const u16* g, u16* l) {
  __builtin_amdgcn_global_load_lds((const __attribute__((address_space(1))) void*)g,
                                   (__attribute__((address_space(3))) void*)l,
                                   16, 0, 0);
}

// ---------------------------------------------------------------------------
// PREP (one launch):
//  [0,640)      GroupNorm_s(x) -> W0 [n][p][c] (XCD-clustered work ids)
//  [640,1664)   convert 8 weight matrices f32->bf16; transposes written for
//               wq->11, wk->16, wv->8, wqt->15, wkt->20, wvt->12 (slot units)
//  [1664,1672)  pack 8 biases (f32)
//  [1672,1674)  bvv  = Wo.bv         at bdst+4096
//  [1674,1676)  bovt = Wot.bvt + bot at bdst+4608
//  [1676,1678)  w_s  = Wk^T.bq       at bdst+5120  (scores col-bias vector)
//  [1678,1680)  w_t  = Wkt^T.bqt     at bdst+5632  (temporal col-bias vector)
//  [1680,1760)  zero softmax stats (20x1024 f32) at bdst+8192
// ---------------------------------------------------------------------------
__global__ __launch_bounds__(256)
void prep(const float* __restrict__ x, const float* __restrict__ gamma,
          const float* __restrict__ beta, u16* __restrict__ gnout,
          const float* __restrict__ w0, const float* __restrict__ w1,
          const float* __restrict__ w2, const float* __restrict__ w3,
          const float* __restrict__ w4, const float* __restrict__ w5,
          const float* __restrict__ w6, const float* __restrict__ w7,
          const float* __restrict__ b0, const float* __restrict__ b1,
          const float* __restrict__ b2, const float* __restrict__ b3,
          const float* __restrict__ b4, const float* __restrict__ b5,
          const float* __restrict__ b6, const float* __restrict__ b7,
          u16* __restrict__ dst, float* __restrict__ bdst)
{
  const int t = threadIdx.x;
  if (blockIdx.x < 640) {                   // ---- GroupNorm_s ----
    const int w = (blockIdx.x & 7) * 80 + (blockIdx.x >> 3);  // XCD-cluster
    const int n = w >> 5, g = w & 31;
    const int C = 512, HW = 1024;
    const float* xg = x + ((long)n * C + g * 16) * HW;
    float s = 0.f, ss = 0.f;
    for (int ch = t; ch < 4096; ch += 256) {
      float4 u = *(const float4*)(xg + ch * 4);
      s += u.x + u.y + u.z + u.w;
      ss += u.x * u.x + u.y * u.y + u.z * u.z + u.w * u.w;
    }
#pragma unroll
    for (int off = 32; off > 0; off >>= 1) { s += __shfl_xor(s, off); ss += __shfl_xor(ss, off); }
    __shared__ float rs[4], rss[4];
    if ((t & 63) == 0) { rs[t >> 6] = s; rss[t >> 6] = ss; }
    __syncthreads();
    s  = rs[0] + rs[1] + rs[2] + rs[3];
    ss = rss[0] + rss[1] + rss[2] + rss[3];
    const float mu = s * (1.f / 16384.f);
    const float var = ss * (1.f / 16384.f) - mu * mu;
    const float rstd = rsqrtf(var + 1e-6f);
    float gm[16], bt[16];
#pragma unroll
    for (int i = 0; i < 16; ++i) {
      float ga = gamma[g * 16 + i];
      gm[i] = ga * rstd;
      bt[i] = beta[g * 16 + i] - mu * ga * rstd;
    }
    for (int p = t; p < 1024; p += 256) {
      alignas(16) u16 vals[16];
#pragma unroll
      for (int i = 0; i < 16; ++i)
        vals[i] = f2b(xg[(long)i * HW + p] * gm[i] + bt[i]);
      u16* dp = gnout + ((long)n * HW + p) * C + g * 16;
      *(uint4*)dp       = *(const uint4*)&vals[0];
      *(uint4*)(dp + 8) = *(const uint4*)&vals[8];
    }
    return;
  }
  const int sb = blockIdx.x - 640;          // ---- setup ----
  if (sb >= 1040) {                         // zero softmax stats
    bdst[8192 + (sb - 1040) * 256 + t] = 0.f;
    return;
  }
  if (sb >= 1038) {                         // w_t = Wkt^T . bqt
    const int d = (sb - 1038) * 256 + t;
    float acc = 0.f;
    for (int e = 0; e < 512; ++e) acc += w5[(long)e * 512 + d] * b4[e];
    bdst[5632 + d] = acc;
    return;
  }
  if (sb >= 1036) {                         // w_s = Wk^T . bq
    const int d = (sb - 1036) * 256 + t;
    float acc = 0.f;
    for (int e = 0; e < 512; ++e) acc += w1[(long)e * 512 + d] * b0[e];
    bdst[5120 + d] = acc;
    return;
  }
  if (sb >= 1034) {                         // bovt = Wot.bvt + bot
    const int a = (sb - 1034) * 256 + t;
    float acc = 0.f;
    for (int c = 0; c < 512; ++c) acc += w7[a * 512 + c] * b6[c];
    bdst[4608 + a] = acc + b7[a];
    return;
  }
  if (sb >= 1032) {                         // bvv = Wo . bv
    const int a = (sb - 1032) * 256 + t;
    float acc = 0.f;
    for (int c = 0; c < 512; ++c) acc += w3[a * 512 + c] * b2[c];
    bdst[4096 + a] = acc;
    return;
  }
  if (sb >= 1024) {                         // biases
    const float* bs8[8] = {b0, b1, b2, b3, b4, b5, b6, b7};
    const int a = sb - 1024;
    bdst[a * 512 + t] = bs8[a][t];
    bdst[a * 512 + t + 256] = bs8[a][t + 256];
    return;
  }
  const float* srcs[8] = {w0, w1, w2, w3, w4, w5, w6, w7};
  const int mat = sb >> 7;
  const int i = (((sb & 127) << 8) + t) * 8;
  const float* s = srcs[mat];
  float4 a = *(const float4*)(s + i);
  float4 b = *(const float4*)(s + i + 4);
  alignas(16) u16 v[8] = {f2b(a.x), f2b(a.y), f2b(a.z), f2b(a.w),
                          f2b(b.x), f2b(b.y), f2b(b.z), f2b(b.w)};
  *(uint4*)(dst + (long)mat * 262144 + i) = *(const uint4*)v;
  // transposes feeding the z=4 weight GEMM (slot layout, stride-4 families):
  //   A:  3=wo, 7=wot, 11=WqT, 15=WqtT;  Bt: 8=WvT, 12=WvtT, 16=WkT, 20=WktT
  const int tmap[8] = {11, 16, 8, -1, 15, 20, 12, -1};
  const int ts = tmap[mat];
  if (ts >= 0) {
    const int row = i >> 9, col = i & 511;
#pragma unroll
    for (int j = 0; j < 8; ++j) dst[(long)ts * 262144 + (col + j) * 512 + row] = v[j];
  }
}

// ---------------------------------------------------------------------------
// Shared GEMM body: BM=BN=128, BK=32, 256 threads (4 waves 2x2 of 64x64),
// 16x16x32 bf16 MFMA, XOR-swizzled LDS (0 conflicts), LDS double-buffer.
// BIASMODE: 0 none, 1 bias[row], 2 bias[col].
// SMEXP: epilogue writes exp((acc+colbias)*alpha), row sums -> stats.
// COLSCALE: epilogue multiplies col cc by 1/stats[stb+cc].
// COLB: per-z column bias (cbias[cbb+cc]) added PRE-exp (QK bias fold term).
// ---------------------------------------------------------------------------
template<int OUTF32, int BIASMODE, int RESID, int SMEXP, int COLSCALE, int COLB>
DI void gemm_body(const u16* __restrict__ Ab, long lda,
                  const u16* __restrict__ Bb, long ldb,
                  void* __restrict__ C, long cb,
                  const float* __restrict__ bias,
                  const float* __restrict__ resid, long rb,
                  int N, int K, float alpha,
                  float* __restrict__ stats, long stb,
                  const float* __restrict__ cbias, long cbb,
                  int m0, int n0, u16* lA, u16* lB)
{
  const int t = threadIdx.x;
  const int lane = t & 63;
  const int wid = t >> 6;
  const int row = t >> 2;                              // 0..63
  const int kc  = (((t & 3) ^ ((t >> 3) & 3)) << 3);   // swizzled staged chunk

  f32x4 acc[4][4];
#pragma unroll
  for (int i = 0; i < 4; ++i)
#pragma unroll
    for (int j = 0; j < 4; ++j) acc[i][j] = (f32x4){0.f, 0.f, 0.f, 0.f};

  const int ml = lane & 15, qd = lane >> 4;
  const int koff = ((qd ^ ((ml >> 1) & 3)) << 3);      // swizzled read offset
  const int wm = (wid >> 1) * 64, wn = (wid & 1) * 64;

  auto stage = [&](int bsel, int k0) {
    const u16* Ap = Ab + (long)(m0 + row) * lda + (k0 + kc);
    const u16* Bp = Bb + (long)(n0 + row) * ldb + (k0 + kc);
    u16* la = lA + bsel * 4096 + wid * 512;
    u16* lb = lB + bsel * 4096 + wid * 512;
    gld_lds16(Ap, la);
    gld_lds16(Ap + 64 * lda, la + 2048);
    gld_lds16(Bp, lb);
    gld_lds16(Bp + 64 * ldb, lb + 2048);
  };

  const int niter = K >> 5;
  stage(0, 0);
  for (int i = 0; i < niter; ++i) {
    __syncthreads();                       // drains buf[i&1] prefetch
    if (i + 1 < niter) stage((i + 1) & 1, (i + 1) << 5);  // overlaps MFMA below
    const u16* la = lA + (i & 1) * 4096;
    const u16* lb = lB + (i & 1) * 4096;
    bf16x8 af[4], bfr[4];
#pragma unroll
    for (int x = 0; x < 4; ++x)
      af[x] = *(const bf16x8*)&la[(wm + x * 16 + ml) * 32 + koff];
#pragma unroll
    for (int y = 0; y < 4; ++y)
      bfr[y] = *(const bf16x8*)&lb[(wn + y * 16 + ml) * 32 + koff];
#pragma unroll
    for (int x = 0; x < 4; ++x)
#pragma unroll
      for (int y = 0; y < 4; ++y)
        acc[x][y] = __builtin_amdgcn_mfma_f32_16x16x32_bf16(af[x], bfr[y], acc[x][y], 0, 0, 0);
  }

  float inv[4], bcol[4], cbl[4];
  if (COLSCALE) {
#pragma unroll
    for (int j = 0; j < 4; ++j)
      inv[j] = 1.f / stats[stb + n0 + wn + j * 16 + ml];
  }
  if (BIASMODE == 2) {
#pragma unroll
    for (int j = 0; j < 4; ++j) bcol[j] = bias[n0 + wn + j * 16 + ml];
  }
  if (COLB) {
#pragma unroll
    for (int j = 0; j < 4; ++j) cbl[j] = cbias[cbb + n0 + wn + j * 16 + ml];
  }
  if (SMEXP) {
    float rs[16];
#pragma unroll
    for (int s = 0; s < 16; ++s) rs[s] = 0.f;
#pragma unroll
    for (int i = 0; i < 4; ++i)
#pragma unroll
      for (int j = 0; j < 4; ++j)
#pragma unroll
        for (int r2 = 0; r2 < 4; ++r2) {
          float sv = acc[i][j][r2];
          if (COLB) sv += cbl[j];
          float e = __expf(sv * alpha);
          acc[i][j][r2] = e;
          rs[i * 4 + r2] += e;
        }
#pragma unroll
    for (int m = 1; m < 16; m <<= 1)
#pragma unroll
      for (int s = 0; s < 16; ++s) rs[s] += __shfl_xor(rs[s], m);
    if (ml == 0) {
#pragma unroll
      for (int i = 0; i < 4; ++i)
#pragma unroll
        for (int r2 = 0; r2 < 4; ++r2)
          atomicAdd(&stats[stb + m0 + wm + i * 16 + qd * 4 + r2], rs[i * 4 + r2]);
    }
  }

#pragma unroll
  for (int i = 0; i < 4; ++i) {
#pragma unroll
    for (int r2 = 0; r2 < 4; ++r2) {
      const int rr = m0 + wm + i * 16 + qd * 4 + r2;  // C/D row = quad*4+reg
      const float brow = (BIASMODE == 1) ? bias[rr] : 0.f;
      const long base = (long)rr * N + n0 + wn + ml;  // col = lane&15 (+j*16)
#pragma unroll
      for (int j = 0; j < 4; ++j) {
        float v = acc[i][j][r2];
        if (!SMEXP) v *= alpha;
        if (COLSCALE) v *= inv[j];
        if (BIASMODE == 1) v += brow;
        if (BIASMODE == 2) v += bcol[j];
        const long ix = base + j * 16;
        if (RESID) v += resid[rb + ix];
        if (OUTF32) ((float*)C)[cb + ix] = v;
        else        ((u16*)C)[cb + ix] = f2b(v);
      }
    }
  }
}

// Generic batched GEMM with z-clustered XCD remap (verified R7).
template<int OUTF32, int BIASMODE, int RESID, int SMEXP, int COLSCALE, int COLB>
__global__ __launch_bounds__(256)
void gemm_bt(const u16* __restrict__ A, long sA, long lda,
             const u16* __restrict__ B, long sB, long ldb,
             void* __restrict__ C, long sC,
             const float* __restrict__ bias,
             const float* __restrict__ resid, long sR,
             int N, int K, float alpha, float* __restrict__ stats,
             const float* __restrict__ cbias)
{
  __shared__ u16 lA[2 * 128 * 32];
  __shared__ u16 lB[2 * 128 * 32];
  const uint32_t nx = gridDim.x, ny = gridDim.y;
  const uint32_t tpz = nx * ny;
  const uint32_t nblk = tpz * gridDim.z;
  const uint32_t g = ((uint32_t)blockIdx.z * ny + blockIdx.y) * nx + blockIdx.x;
  const uint32_t idx = (g & 7u) * (nblk >> 3) + (g >> 3);
  const uint32_t bz = idx / tpz;
  const uint32_t r   = idx - bz * tpz;
  const int m0 = (int)(r / nx) * 128, n0 = (int)(r % nx) * 128;
  gemm_body<OUTF32, BIASMODE, RESID, SMEXP, COLSCALE, COLB>(
      A + bz * sA, lda, B + bz * sB, ldb, C, bz * sC, bias, resid, bz * sR,
      N, K, alpha, stats, (long)bz * 1024, cbias, (long)bz * 1024,
      m0, n0, lA, lB);
}

// ---------------------------------------------------------------------------
// Merged colterm || mkT || vv launch (all depend only on prep + weight GEMM):
//  [0,80):      colterm[row] = dot(hn[row], w_s) -> colt[20480] (f32)
//               FIRST so its latency chain hides under the GEMM partitions
//               (R11 lesson: at the tail it added ~15us of serial latency).
//               8-way row ILP: 8 independent loads in flight per wave.
//  [80,720):    mkT = hn.M_s^T  (M=20480, N=512, K=512) -> W1 [20480][512]
//  [720,1360):  vv  = Wov.hn^T + bvv (z=20, M=512, N=1024) -> W3 [20][c][p]
// Partition offsets multiples of 8 keep XCD parity for the remaps.
// ---------------------------------------------------------------------------
__global__ __launch_bounds__(256)
void gemm_mkvv(const u16* __restrict__ hn, const u16* __restrict__ Ms,
               u16* __restrict__ mkout,
               const u16* __restrict__ Wov, u16* __restrict__ vvout,
               const float* __restrict__ bvv,
               const float* __restrict__ ws, float* __restrict__ colt)
{
  __shared__ u16 lA[2 * 128 * 32];
  __shared__ u16 lB[2 * 128 * 32];
  const long S = 524288;
  const int t = threadIdx.x;
  const uint32_t g = blockIdx.x;
  if (g < 80) {                             // ---- colterm (QK bias fold) ----
    const int lane = t & 63, wv = t >> 6;
    float wsv[8];
#pragma unroll
    for (int u = 0; u < 8; ++u) wsv[u] = ws[lane * 8 + u];
    const int row0 = (int)g * 256 + wv * 64;
    for (int rr = 0; rr < 64; rr += 8) {
      float a[8];
#pragma unroll
      for (int u8 = 0; u8 < 8; ++u8) {      // 8 independent loads in flight
        bf16x8 hv = *(const bf16x8*)(hn + (long)(row0 + rr + u8) * 512 + lane * 8);
        float s = 0.f;
#pragma unroll
        for (int u = 0; u < 8; ++u) s += b2f((u16)hv[u]) * wsv[u];
        a[u8] = s;
      }
#pragma unroll
      for (int off = 32; off > 0; off >>= 1)
#pragma unroll
        for (int u8 = 0; u8 < 8; ++u8) a[u8] += __shfl_xor(a[u8], off);
      if (lane == 0) {
#pragma unroll
        for (int u8 = 0; u8 < 8; ++u8) colt[row0 + rr + u8] = a[u8];
      }
    }
  } else if (g < 720) {                     // ---- mkT ----
    const uint32_t gg = g - 80;             // 80%8==0 keeps parity
    const uint32_t idx = (gg & 7u) * 80 + (gg >> 3);
    const int m0 = (int)(idx >> 2) * 128, n0 = (int)(idx & 3u) * 128;
    gemm_body<0, 0, 0, 0, 0, 0>(hn, 512, Ms, 512, mkout, 0, nullptr,
                                nullptr, 0, 512, 512, 1.f, nullptr, 0,
                                nullptr, 0, m0, n0, lA, lB);
  } else {                                  // ---- vv ----
    const uint32_t gg = g - 720;            // 720%8==0 keeps parity
    const uint32_t idx = (gg & 7u) * 80 + (gg >> 3);
    const uint32_t bz = idx >> 5;           // 32 tiles per z
    const uint32_t r = idx & 31u;
    const int m0 = (int)(r >> 3) * 128, n0 = (int)(r & 7u) * 128;
    gemm_body<0, 1, 0, 0, 0, 0>(Wov, 512, hn + (long)bz * S, 512, vvout,
                                (long)bz * S, bvv, nullptr, 0,
                                1024, 512, 1.f, nullptr, 0, nullptr, 0,
                                m0, n0, lA, lB);
  }
}

// ---------------------------------------------------------------------------
// GroupNorm with fused residual: spatio = x (f32) + h (bf16 conv out), then
// GroupNorm -> bf16 out TRANSPOSED to [n][p][c]. XCD-clustered work ids.
// ---------------------------------------------------------------------------
__global__ __launch_bounds__(256)
void groupnorm_resid(const u16* __restrict__ h, const float* __restrict__ x,
                     const float* __restrict__ gamma,
                     const float* __restrict__ beta, u16* __restrict__ out)
{
  const int C = 512, HW = 1024;
  const int w = (blockIdx.x & 7) * 80 + (blockIdx.x >> 3);    // XCD-cluster
  const int n = w >> 5, g = w & 31;
  const long base = ((long)n * C + g * 16) * HW;
  const float* xg = x + base;
  const u16*  hg = h + base;
  const int t = threadIdx.x;
  float s = 0.f, ss = 0.f;
  for (int ch = t; ch < 4096; ch += 256) {
    float4 u = *(const float4*)(xg + ch * 4);
    uint2 hv = *(const uint2*)(hg + ch * 4);
    float h0 = __uint_as_float(hv.x << 16);
    float h1 = __uint_as_float(hv.x & 0xffff0000u);
    float h2 = __uint_as_float(hv.y << 16);
    float h3 = __uint_as_float(hv.y & 0xffff0000u);
    float v0 = u.x + h0, v1 = u.y + h1, v2 = u.z + h2, v3 = u.w + h3;
    s += v0 + v1 + v2 + v3;
    ss += v0 * v0 + v1 * v1 + v2 * v2 + v3 * v3;
  }
#pragma unroll
  for (int off = 32; off > 0; off >>= 1) { s += __shfl_xor(s, off); ss += __shfl_xor(ss, off); }
  __shared__ float rs[4], rss[4];
  if ((t & 63) == 0) { rs[t >> 6] = s; rss[t >> 6] = ss; }
  __syncthreads();
  s  = rs[0] + rs[1] + rs[2] + rs[3];
  ss = rss[0] + rss[1] + rss[2] + rss[3];
  const float mu = s * (1.f / 16384.f);
  const float var = ss * (1.f / 16384.f) - mu * mu;
  const float rstd = rsqrtf(var + 1e-6f);
  float gm[16], bt[16];
#pragma unroll
  for (int i = 0; i < 16; ++i) {
    float ga = gamma[g * 16 + i];
    gm[i] = ga * rstd;
    bt[i] = beta[g * 16 + i] - mu * ga * rstd;
  }
  for (int p = t; p < 1024; p += 256) {
    alignas(16) u16 vals[16];
#pragma unroll
    for (int i = 0; i < 16; ++i)
      vals[i] = f2b((xg[(long)i * HW + p] + b2f(hg[(long)i * HW + p])) * gm[i] + bt[i]);
    u16* dst = out + ((long)n * HW + p) * C + g * 16;
    *(uint4*)dst       = *(const uint4*)&vals[0];
    *(uint4*)(dst + 8) = *(const uint4*)&vals[8];
  }
}

// ---------------------------------------------------------------------------
// Temporal attention (QK + Wovt folded): one WAVE per pixel (b,p).
// Q = hn_t row (also reused as V); K = mkt row (= hn_t.M_t^T). Bias fold:
// ct[j] = dot(hn_t[j], w_t) added to scores pre-softmax (row term cancels).
// Output htp' = sum_s att[i][s]*hn_t[s] -> [20480][512].
// ---------------------------------------------------------------------------
__global__ __launch_bounds__(256)
void temporal_attn(const u16* __restrict__ mkt, const u16* __restrict__ hn,
                   u16* __restrict__ htp, const float* __restrict__ wt)
{
  const int t = threadIdx.x;
  const int wv = t >> 6, lane = t & 63;
  const int pix = blockIdx.x * 4 + wv;      // 0..4095 = (b, p)
  const int b = pix >> 10, p = pix & 1023;
  const long fsh = 1024l * 512;             // frame stride (hn/mkt/htp)
  const long rowh = ((long)b * 5 * 1024 + p) * 512 + lane * 8;

  float wtv[8];
#pragma unroll
  for (int u = 0; u < 8; ++u) wtv[u] = wt[lane * 8 + u];

  float qf[5][8], kf[5][8];
#pragma unroll
  for (int f = 0; f < 5; ++f) {
    bf16x8 qv = *(const bf16x8*)(hn  + rowh + f * fsh);
    bf16x8 kv = *(const bf16x8*)(mkt + rowh + f * fsh);
#pragma unroll
    for (int u = 0; u < 8; ++u) { qf[f][u] = b2f((u16)qv[u]); kf[f][u] = b2f((u16)kv[u]); }
  }
  float sc[30];                             // 25 scores + 5 colterms
#pragma unroll
  for (int i = 0; i < 5; ++i)
#pragma unroll
    for (int j = 0; j < 5; ++j) {
      float a = 0.f;
#pragma unroll
      for (int u = 0; u < 8; ++u) a += qf[i][u] * kf[j][u];
      sc[i * 5 + j] = a;
    }
#pragma unroll
  for (int f = 0; f < 5; ++f) {
    float a = 0.f;
#pragma unroll
    for (int u = 0; u < 8; ++u) a += qf[f][u] * wtv[u];
    sc[25 + f] = a;
  }
#pragma unroll
  for (int m = 1; m < 64; m <<= 1)
#pragma unroll
    for (int s = 0; s < 30; ++s) sc[s] += __shfl_xor(sc[s], m);

  const float scale = 0.04419417382415922f;  // 512^-0.5
  float att[5][5];
#pragma unroll
  for (int i = 0; i < 5; ++i) {
    float sf[5];
#pragma unroll
    for (int j = 0; j < 5; ++j) sf[j] = sc[i * 5 + j] + sc[25 + j];
    float m = sf[0];
#pragma unroll
    for (int j = 1; j < 5; ++j) m = fmaxf(m, sf[j]);
    float ssum = 0.f;
#pragma unroll
    for (int j = 0; j < 5; ++j) { att[i][j] = __expf((sf[j] - m) * scale); ssum += att[i][j]; }
    float inv = 1.f / ssum;
#pragma unroll
    for (int j = 0; j < 5; ++j) att[i][j] *= inv;
  }

  float of[5][8];
#pragma unroll
  for (int i = 0; i < 5; ++i)
#pragma unroll
    for (int u = 0; u < 8; ++u) of[i][u] = 0.f;
#pragma unroll
  for (int s = 0; s < 5; ++s)               // V = hn_t rows, already in qf
#pragma unroll
    for (int u = 0; u < 8; ++u) {
      const float vf = qf[s][u];
#pragma unroll
      for (int i = 0; i < 5; ++i) of[i][u] += att[i][s] * vf;
    }
#pragma unroll
  for (int i = 0; i < 5; ++i) {
    alignas(16) u16 ob[8];
#pragma unroll
    for (int u = 0; u < 8; ++u) ob[u] = f2b(of[i][u]);
    *(uint4*)(htp + rowh + i * fsh) = *(const uint4*)ob;
  }
}

// ---------------------------------------------------------------------------
extern "C" void kernel_launch(void* const* d_in, const int* in_sizes, int n_in,
                              void* d_out, int out_size, void* d_ws, size_t ws_size,
                              hipStream_t stream)
{
  const float* x   = (const float*)d_in[0];
  const float* wq  = (const float*)d_in[1];
  const float* bq  = (const float*)d_in[2];
  const float* wk  = (const float*)d_in[3];
  const float* bk  = (const float*)d_in[4];
  const float* wv  = (const float*)d_in[5];
  const float* bv  = (const float*)d_in[6];
  const float* wo  = (const float*)d_in[7];
  const float* bo  = (const float*)d_in[8];
  const float* wqt = (const float*)d_in[9];
  const float* bqt = (const float*)d_in[10];
  const float* wkt = (const float*)d_in[11];
  const float* bkt = (const float*)d_in[12];
  const float* wvt = (const float*)d_in[13];
  const float* bvt = (const float*)d_in[14];
  const float* wot = (const float*)d_in[15];
  const float* bot = (const float*)d_in[16];
  const float* gs  = (const float*)d_in[17];
  const float* bs  = (const float*)d_in[18];
  const float* gt  = (const float*)d_in[19];
  const float* btt = (const float*)d_in[20];

  // ws = 256 MiB. Slots W0..W7 (8 x 20 MB), weights Wt (22 x 0.5 MB), biases.
  const long U = 20l * 1024 * 512;          // elements per slot
  u16* W0 = (u16*)d_ws;
  u16* W1 = W0 + U;                          // mkT / mkt [20480][512]
  u16* W3 = W0 + 3 * U;                      // vv [20][c][p]
  u16* W4 = W0 + 4 * U;                      // W4..W5 scores [20][1024][1024]
  u16* W6 = W0 + 6 * U;                      // hsp_conv [20][c][p]
  u16* W7 = W0 + 7 * U;                      // hn_t [n][p][c]
  u16* Wt = W0 + 8 * U;
  // weight slot layout (stride-4 families for the z=4 weight GEMM):
  //  0..7 converted; A: 3=wo,7=wot,11=WqT,15=WqtT; Bt: 8=WvT,12=WvtT,16=WkT,
  //  20=WktT; C: 9=Wov,13=Wovt,17=M_s,21=M_t.
  u16* wo_b   = Wt + 3 * 262144;
  u16* wvT_b  = Wt + 8 * 262144;
  u16* Wovs   = Wt + 9 * 262144;
  u16* Wovt_b = Wt + 13 * 262144;
  u16* Ms_b   = Wt + 17 * 262144;
  u16* Mt_b   = Wt + 21 * 262144;
  float* Bf = (float*)(Wt + 22 * 262144);    // biases; bvv@4096; bovt@4608;
  float* Ws_v = Bf + 5120;                   // w_s vector
  float* Wt_v = Bf + 5632;                   // w_t vector
  float* Stats = Bf + 8192;                  // 20x1024 softmax row sums
  float* Colt  = Bf + 28672;                 // 20x1024 scores col-bias

  const long S  = 524288;                   // 1024*512 per-image stride
  const long S2 = 1048576;                  // 1024*1024 per-image stride
  const float scale = 0.04419417382415922f; // 512^-0.5
  dim3 blk(256);

  // prep: GroupNorm_s + weight convert (+6 transposes) + biases + folded
  // bias vectors + stats zero
  prep<<<1760, blk, 0, stream>>>(x, gs, bs, W0,
                                 wq, wk, wv, wo, wqt, wkt, wvt, wot,
                                 bq, bk, bv, bo, bqt, bkt, bvt, bot, Wt, Bf);

  // Weight GEMM (z=4): Wov = Wo.Wv; Wovt = Wot.Wvt; M_s = Wq^T.Wk;
  // M_t = Wqt^T.Wkt  (uniform stride-4-slot families)
  gemm_bt<0, 0, 0, 0, 0, 0><<<dim3(4, 4, 4), blk, 0, stream>>>(
      wo_b, 4 * 262144, 512, wvT_b, 4 * 262144, 512, Wovs, 4 * 262144,
      nullptr, nullptr, 0, 512, 512, 1.f, nullptr, nullptr);

  // colterm || mkT || vv merged: 80 + 640 + 640 blocks (colterm first)
  gemm_mkvv<<<1360, blk, 0, stream>>>(W0, Ms_b, W1, Wovs, W3, Bf + 4096,
                                      Ws_v, Colt);

  // att_exp = exp((hn.mkT^T + colterm) * scale) -> W4W5; row sums -> Stats
  gemm_bt<0, 0, 0, 1, 0, 1><<<dim3(8, 8, 20), blk, 0, stream>>>(
      W0, S, 512, W1, S, 512, W4, S2, nullptr, nullptr, 0,
      1024, 512, scale, Stats, Colt);
  // hsp_conv = (vv.att_exp^T) * inv[pq] + bo: z=20, M=c', N=pq, K=pk -> W6
  gemm_bt<0, 1, 0, 0, 1, 0><<<dim3(8, 4, 20), blk, 0, stream>>>(
      W3, S, 1024, W4, S2, 1024, W6, S, Bf + 1536, nullptr, 0,
      1024, 1024, 1.f, Stats, nullptr);
  // hn_t = GroupNorm_t(x + W6) -> W7 [n][p][c]  (resid fused here)
  groupnorm_resid<<<640, blk, 0, stream>>>(W6, x, gt, btt, W7);
  // mkt = hn_t.M_t^T: M=20480, N=512, K=512 -> W1 [20480][512]
  gemm_bt<0, 0, 0, 0, 0, 0><<<dim3(4, 160, 1), blk, 0, stream>>>(
      W7, 0, 512, Mt_b, 0, 512, W1, 0, nullptr, nullptr, 0,
      512, 512, 1.f, nullptr, nullptr);
  // per-pixel 5x5 temporal attention (Q=V=hn_t, K=mkt) -> W0 htp' [20480][512]
  temporal_attn<<<1024, blk, 0, stream>>>(W1, W7, W0, Wt_v);
  // out = x + Wovt.htp' + (Wot.bvt + bot) -> d_out f32, z=20
  gemm_bt<1, 1, 1, 0, 0, 0><<<dim3(8, 4, 20), blk, 0, stream>>>(
      Wovt_b, 0, 512, W0, S, 512, (float*)d_out, S, Bf + 4608, x, S,
      1024, 512, 1.f, nullptr, nullptr);
}